// Round 1
// baseline (8377.238 us; speedup 1.0000x reference)
//
#include <hip/hip_runtime.h>
#include <cmath>

#define TPB 256
#define NSLOPE 0.2f
#define SEPS 1e-16f

__device__ __forceinline__ unsigned f2u_order(float f) {
    unsigned u = __float_as_uint(f);
    return (u & 0x80000000u) ? ~u : (u | 0x80000000u);
}
__device__ __forceinline__ float u2f_order(unsigned u) {
    return (u & 0x80000000u) ? __uint_as_float(u & 0x7FFFFFFFu)
                             : __uint_as_float(~u);
}
__device__ __forceinline__ float lrelu(float v) { return v > 0.f ? v : NSLOPE * v; }
__device__ __forceinline__ float elu1(float v)  { return v > 0.f ? v : expm1f(v); }

// ---- layer-1 scalar prep: S1[h] = sum_c W1[h*8+c]*att_src1[h*8+c], D1 likewise ----
__global__ void k_prep1(const float* __restrict__ W1, const float* __restrict__ as1,
                        const float* __restrict__ ad1, float* __restrict__ SD) {
    int t = threadIdx.x;
    if (t < 8) {
        int h = t & 3;
        const float* att = (t >= 4) ? ad1 : as1;
        float acc = 0.f;
        #pragma unroll
        for (int c = 0; c < 8; ++c) acc += W1[h*8+c] * att[h*8+c];
        SD[t] = acc;   // SD[0..3]=S1, SD[4..7]=D1
    }
}

// ---- layer 1 edge passes (H=4), logit = x[s]*S1[h] + x[d]*D1[h] ----
__global__ void k_edge_max1(const int* __restrict__ srcI, const int* __restrict__ dstI,
                            int E, int N, const float* __restrict__ x,
                            const float* __restrict__ SD, unsigned* __restrict__ m1) {
    int e = blockIdx.x * blockDim.x + threadIdx.x;
    if (e >= E + N) return;
    int s, d;
    if (e < E) { s = srcI[e]; d = dstI[e]; } else { s = d = e - E; }
    float xs = x[s], xd = x[d];
    #pragma unroll
    for (int h = 0; h < 4; ++h) {
        float v = lrelu(xs * SD[h] + xd * SD[4+h]);
        atomicMax(&m1[d*4+h], f2u_order(v));
    }
}

__global__ void k_edge_sum1(const int* __restrict__ srcI, const int* __restrict__ dstI,
                            int E, int N, const float* __restrict__ x,
                            const float* __restrict__ SD, const unsigned* __restrict__ m1,
                            float* __restrict__ s1) {
    int e = blockIdx.x * blockDim.x + threadIdx.x;
    if (e >= E + N) return;
    int s, d;
    if (e < E) { s = srcI[e]; d = dstI[e]; } else { s = d = e - E; }
    float xs = x[s], xd = x[d];
    #pragma unroll
    for (int h = 0; h < 4; ++h) {
        float v = lrelu(xs * SD[h] + xd * SD[4+h]);
        float p = expf(v - u2f_order(m1[d*4+h]));
        atomicAdd(&s1[d*4+h], p);
    }
}

__global__ void k_edge_agg1(const int* __restrict__ srcI, const int* __restrict__ dstI,
                            int E, int N, const float* __restrict__ x,
                            const float* __restrict__ SD, const unsigned* __restrict__ m1,
                            const float* __restrict__ s1, const float* __restrict__ W1,
                            float* __restrict__ out1) {
    int e = blockIdx.x * blockDim.x + threadIdx.x;
    if (e >= E + N) return;
    int s, d;
    if (e < E) { s = srcI[e]; d = dstI[e]; } else { s = d = e - E; }
    float xs = x[s], xd = x[d];
    #pragma unroll
    for (int h = 0; h < 4; ++h) {
        float v = lrelu(xs * SD[h] + xd * SD[4+h]);
        float p = expf(v - u2f_order(m1[d*4+h]));
        float alpha = p / (s1[d*4+h] + SEPS);
        float t = alpha * xs;           // h1[src,h,c] = x[src]*W1[h*8+c]
        #pragma unroll
        for (int c = 0; c < 8; ++c)
            atomicAdd(&out1[d*32 + h*8 + c], t * W1[h*8+c]);
    }
}

// ---- elementwise: out[i] = elu(out[i] + bias[i & mask]) ----
__global__ void k_elu_bias(float* __restrict__ buf, const float* __restrict__ bias,
                           int n, int mask) {
    int i = blockIdx.x * blockDim.x + threadIdx.x;
    if (i >= n) return;
    buf[i] = elu1(buf[i] + bias[i & mask]);
}

// ---- h2[n,j] = sum_k h1p[n,k] * W2[k,j]  (32x64) ----
__global__ void k_h2(const float* __restrict__ h1p, const float* __restrict__ W2,
                     float* __restrict__ h2, int N) {
    int i = blockIdx.x * blockDim.x + threadIdx.x;
    if (i >= N * 64) return;
    int n = i >> 6, j = i & 63;
    const float* row = h1p + n * 32;
    float acc = 0.f;
    #pragma unroll
    for (int k = 0; k < 32; ++k) acc += row[k] * W2[k*64 + j];
    h2[i] = acc;
}

// ---- per-(n,h) attention coefficients, layer 2 ----
__global__ void k_att2(const float* __restrict__ h2, const float* __restrict__ attS,
                       const float* __restrict__ attD, float* __restrict__ aS,
                       float* __restrict__ aD, int N) {
    int i = blockIdx.x * blockDim.x + threadIdx.x;
    if (i >= N * 8) return;
    int n = i >> 3, h = i & 7;
    const float* row = h2 + n*64 + h*8;
    float as = 0.f, ad = 0.f;
    #pragma unroll
    for (int c = 0; c < 8; ++c) { float v = row[c]; as += v*attS[h*8+c]; ad += v*attD[h*8+c]; }
    aS[i] = as; aD[i] = ad;
}

// ---- layer 2 edge passes (H=8) ----
__global__ void k_edge_max2(const int* __restrict__ srcI, const int* __restrict__ dstI,
                            int E, int N, const float* __restrict__ aS,
                            const float* __restrict__ aD, unsigned* __restrict__ m2) {
    int e = blockIdx.x * blockDim.x + threadIdx.x;
    if (e >= E + N) return;
    int s, d;
    if (e < E) { s = srcI[e]; d = dstI[e]; } else { s = d = e - E; }
    #pragma unroll
    for (int h = 0; h < 8; ++h) {
        float v = lrelu(aS[s*8+h] + aD[d*8+h]);
        atomicMax(&m2[d*8+h], f2u_order(v));
    }
}

__global__ void k_edge_sum2(const int* __restrict__ srcI, const int* __restrict__ dstI,
                            int E, int N, const float* __restrict__ aS,
                            const float* __restrict__ aD, const unsigned* __restrict__ m2,
                            float* __restrict__ s2) {
    int e = blockIdx.x * blockDim.x + threadIdx.x;
    if (e >= E + N) return;
    int s, d;
    if (e < E) { s = srcI[e]; d = dstI[e]; } else { s = d = e - E; }
    #pragma unroll
    for (int h = 0; h < 8; ++h) {
        float v = lrelu(aS[s*8+h] + aD[d*8+h]);
        float p = expf(v - u2f_order(m2[d*8+h]));
        atomicAdd(&s2[d*8+h], p);
    }
}

// one thread per (edge, head)
__global__ void k_edge_agg2(const int* __restrict__ srcI, const int* __restrict__ dstI,
                            int E, int N, const float* __restrict__ aS,
                            const float* __restrict__ aD, const unsigned* __restrict__ m2,
                            const float* __restrict__ s2, const float* __restrict__ h2,
                            float* __restrict__ out2) {
    int i = blockIdx.x * blockDim.x + threadIdx.x;
    if (i >= (E + N) * 8) return;
    int e = i >> 3, h = i & 7;
    int s, d;
    if (e < E) { s = srcI[e]; d = dstI[e]; } else { s = d = e - E; }
    float v = lrelu(aS[s*8+h] + aD[d*8+h]);
    float p = expf(v - u2f_order(m2[d*8+h]));
    float alpha = p / (s2[d*8+h] + SEPS);
    const float* hr = h2 + (size_t)s*64 + h*8;
    float* orow = out2 + (size_t)d*64 + h*8;
    #pragma unroll
    for (int c = 0; c < 8; ++c)
        atomicAdd(&orow[c], alpha * hr[c]);
}

// ---- final: out[n] = sum_j elu(out2[n,j]+b2[j]) * fcw[j] + fcb ----
__global__ void k_final(const float* __restrict__ out2, const float* __restrict__ b2,
                        const float* __restrict__ fcw, const float* __restrict__ fcb,
                        float* __restrict__ out, int N) {
    int n = blockIdx.x * blockDim.x + threadIdx.x;
    if (n >= N) return;
    const float* row = out2 + (size_t)n * 64;
    float acc = fcb[0];
    #pragma unroll
    for (int j = 0; j < 64; ++j) acc += elu1(row[j] + b2[j]) * fcw[j];
    out[n] = acc;
}

extern "C" void kernel_launch(void* const* d_in, const int* in_sizes, int n_in,
                              void* d_out, int out_size, void* d_ws, size_t ws_size,
                              hipStream_t stream) {
    const float* x    = (const float*)d_in[0];
    const int*   ei   = (const int*)  d_in[1];
    const float* W1   = (const float*)d_in[2];
    const float* as1  = (const float*)d_in[3];
    const float* ad1  = (const float*)d_in[4];
    const float* b1   = (const float*)d_in[5];
    const float* W2   = (const float*)d_in[6];
    const float* attS2= (const float*)d_in[7];
    const float* attD2= (const float*)d_in[8];
    const float* b2   = (const float*)d_in[9];
    const float* fcw  = (const float*)d_in[10];
    const float* fcb  = (const float*)d_in[11];
    float* out = (float*)d_out;

    int N = in_sizes[0];          // x is [N,1]
    int E = in_sizes[1] / 2;      // edge_index is [2,E]
    int ET = E + N;               // with self-loops

    float* ws = (float*)d_ws;
    size_t off = 0;
    float*    SD   = ws + off; off += 8;
    // contiguous zero-init block: m1,s1,out1,m2,s2,out2  (N*120 floats)
    unsigned* m1   = (unsigned*)(ws + off); off += (size_t)N*4;
    float*    s1   = ws + off; off += (size_t)N*4;
    float*    out1 = ws + off; off += (size_t)N*32;
    unsigned* m2   = (unsigned*)(ws + off); off += (size_t)N*8;
    float*    s2   = ws + off; off += (size_t)N*8;
    float*    out2 = ws + off; off += (size_t)N*64;
    // fully-overwritten-each-launch block:
    float*    h2   = ws + off; off += (size_t)N*64;
    float*    aS2  = ws + off; off += (size_t)N*8;
    float*    aD2  = ws + off; off += (size_t)N*8;

    const int* srcI = ei;
    const int* dstI = ei + E;

    // zero all accumulators + max buffers in one shot.
    // (f2u_order of any finite float is > 0, and every (node,head) gets at least
    //  its self-loop via atomicMax, so 0 is a valid "-inf" for the max buffers.)
    hipMemsetAsync(m1, 0, (size_t)N * 120 * sizeof(float), stream);

    k_prep1<<<1, 64, 0, stream>>>(W1, as1, ad1, SD);

    int gE = (ET + TPB - 1) / TPB;
    k_edge_max1<<<gE, TPB, 0, stream>>>(srcI, dstI, E, N, x, SD, m1);
    k_edge_sum1<<<gE, TPB, 0, stream>>>(srcI, dstI, E, N, x, SD, m1, s1);
    k_edge_agg1<<<gE, TPB, 0, stream>>>(srcI, dstI, E, N, x, SD, m1, s1, W1, out1);

    k_elu_bias<<<(N*32 + TPB - 1) / TPB, TPB, 0, stream>>>(out1, b1, N*32, 31);
    k_h2<<<(N*64 + TPB - 1) / TPB, TPB, 0, stream>>>(out1, W2, h2, N);
    k_att2<<<(N*8 + TPB - 1) / TPB, TPB, 0, stream>>>(h2, attS2, attD2, aS2, aD2, N);

    k_edge_max2<<<gE, TPB, 0, stream>>>(srcI, dstI, E, N, aS2, aD2, m2);
    k_edge_sum2<<<gE, TPB, 0, stream>>>(srcI, dstI, E, N, aS2, aD2, m2, s2);
    int gE8 = (ET*8 + TPB - 1) / TPB;
    k_edge_agg2<<<gE8, TPB, 0, stream>>>(srcI, dstI, E, N, aS2, aD2, m2, s2, h2, out2);

    k_final<<<(N + TPB - 1) / TPB, TPB, 0, stream>>>(out2, b2, fcw, fcb, out, N);
}

// Round 2
// 536.377 us; speedup vs baseline: 15.6182x; 15.6182x over previous
//
#include <hip/hip_runtime.h>
#include <cmath>

#define TPB 256
#define NSLOPE 0.2f
#define SEPS 1e-16f

__device__ __forceinline__ float lrelu(float v) { return v > 0.f ? v : NSLOPE * v; }
__device__ __forceinline__ float elu1(float v)  { return v > 0.f ? v : expm1f(v); }

// ---- layer-1 scalar prep: SD[0..3]=S1[h]=sum_c W1[h,c]*att_src1[h,c]; SD[4..7]=D1 ----
__global__ void k_prep1(const float* __restrict__ W1, const float* __restrict__ as1,
                        const float* __restrict__ ad1, float* __restrict__ SD) {
    int t = threadIdx.x;
    if (t < 8) {
        int h = t & 3;
        const float* att = (t >= 4) ? ad1 : as1;
        float acc = 0.f;
        #pragma unroll
        for (int c = 0; c < 8; ++c) acc += W1[h*8+c] * att[h*8+c];
        SD[t] = acc;
    }
}

// ---- counting sort of edges by dst: histogram -> scan -> scatter ----
__global__ void k_hist(const int* __restrict__ dstI, int E, int N, int* __restrict__ counts) {
    int e = blockIdx.x * blockDim.x + threadIdx.x;
    if (e >= E + N) return;
    int d = (e < E) ? dstI[e] : (e - E);
    atomicAdd(&counts[d], 1);
}

#define SCAN_B 256
__global__ void k_scan1(const int* __restrict__ counts, int* __restrict__ partial,
                        int* __restrict__ blockSums, int N) {
    __shared__ int tmp[SCAN_B];
    int gid = blockIdx.x * SCAN_B + threadIdx.x;
    int v = (gid < N) ? counts[gid] : 0;
    tmp[threadIdx.x] = v;
    __syncthreads();
    for (int off = 1; off < SCAN_B; off <<= 1) {
        int t = (threadIdx.x >= off) ? tmp[threadIdx.x - off] : 0;
        __syncthreads();
        tmp[threadIdx.x] += t;
        __syncthreads();
    }
    if (gid < N) partial[gid] = tmp[threadIdx.x] - v;          // exclusive within block
    if (threadIdx.x == SCAN_B - 1) blockSums[blockIdx.x] = tmp[SCAN_B - 1];
}

__global__ void k_scan2(int* __restrict__ blockSums, int nb) {
    __shared__ int tmp[512];
    int t = threadIdx.x;
    int v = (t < nb) ? blockSums[t] : 0;
    tmp[t] = v;
    __syncthreads();
    for (int off = 1; off < 512; off <<= 1) {
        int u = (t >= off) ? tmp[t - off] : 0;
        __syncthreads();
        tmp[t] += u;
        __syncthreads();
    }
    if (t < nb) blockSums[t] = tmp[t] - v;                     // exclusive
}

__global__ void k_scan3(const int* __restrict__ partial, const int* __restrict__ blockSums,
                        int* __restrict__ offsets, int* __restrict__ cursor, int N, int ET) {
    int gid = blockIdx.x * blockDim.x + threadIdx.x;
    if (gid >= N) return;
    int v = partial[gid] + blockSums[gid / SCAN_B];
    offsets[gid] = v;
    cursor[gid] = v;
    if (gid == 0) offsets[N] = ET;
}

__global__ void k_scatter(const int* __restrict__ srcI, const int* __restrict__ dstI,
                          int E, int N, int* __restrict__ cursor, int* __restrict__ sortedSrc) {
    int e = blockIdx.x * blockDim.x + threadIdx.x;
    if (e >= E + N) return;
    int s, d;
    if (e < E) { s = srcI[e]; d = dstI[e]; } else { s = d = e - E; }
    int pos = atomicAdd(&cursor[d], 1);
    sortedSrc[pos] = s;
}

// ---- layer 1 fully fused: per-node gather softmax (H=4) -> bias -> ELU ----
// h1[s,h,c] = x[s]*W1[h,c]  =>  sum_e alpha*h1[s] = (sum_e alpha*x[s]) * W1[h,:]
__global__ void k_layer1(const int* __restrict__ offsets, const int* __restrict__ sortedSrc,
                         const float* __restrict__ x, const float* __restrict__ SD,
                         const float* __restrict__ W1, const float* __restrict__ b1,
                         float* __restrict__ out1p, int N) {
    int d = blockIdx.x * blockDim.x + threadIdx.x;
    if (d >= N) return;
    int beg = offsets[d], end = offsets[d+1];
    float xd = x[d];
    float S0 = SD[0], S1 = SD[1], S2 = SD[2], S3 = SD[3];
    float D0 = SD[4], D1 = SD[5], D2 = SD[6], D3 = SD[7];
    float m0 = -3.4e38f, m1 = m0, m2 = m0, m3 = m0;
    for (int i = beg; i < end; ++i) {
        float xs = x[sortedSrc[i]];
        m0 = fmaxf(m0, lrelu(xs*S0 + xd*D0));
        m1 = fmaxf(m1, lrelu(xs*S1 + xd*D1));
        m2 = fmaxf(m2, lrelu(xs*S2 + xd*D2));
        m3 = fmaxf(m3, lrelu(xs*S3 + xd*D3));
    }
    float s0 = 0.f, s1 = 0.f, s2 = 0.f, s3 = 0.f;
    float g0 = 0.f, g1 = 0.f, g2 = 0.f, g3 = 0.f;
    for (int i = beg; i < end; ++i) {
        float xs = x[sortedSrc[i]];
        float p;
        p = expf(lrelu(xs*S0 + xd*D0) - m0); s0 += p; g0 += p * xs;
        p = expf(lrelu(xs*S1 + xd*D1) - m1); s1 += p; g1 += p * xs;
        p = expf(lrelu(xs*S2 + xd*D2) - m2); s2 += p; g2 += p * xs;
        p = expf(lrelu(xs*S3 + xd*D3) - m3); s3 += p; g3 += p * xs;
    }
    float g[4];
    g[0] = g0 / (s0 + SEPS); g[1] = g1 / (s1 + SEPS);
    g[2] = g2 / (s2 + SEPS); g[3] = g3 / (s3 + SEPS);
    float* orow = out1p + (size_t)d * 32;
    #pragma unroll
    for (int h = 0; h < 4; ++h)
        #pragma unroll
        for (int c = 0; c < 8; ++c)
            orow[h*8+c] = elu1(g[h] * W1[h*8+c] + b1[h*8+c]);
}

// ---- h2[n,j] = sum_k out1p[n,k] * W2[k,j]  (32x64) ----
__global__ void k_h2(const float* __restrict__ h1p, const float* __restrict__ W2,
                     float* __restrict__ h2, int N) {
    int i = blockIdx.x * blockDim.x + threadIdx.x;
    if (i >= N * 64) return;
    int n = i >> 6, j = i & 63;
    const float* row = h1p + (size_t)n * 32;
    float acc = 0.f;
    #pragma unroll
    for (int k = 0; k < 32; ++k) acc += row[k] * W2[k*64 + j];
    h2[i] = acc;
}

// ---- per-(n,h) attention coefficients, layer 2 ----
__global__ void k_att2(const float* __restrict__ h2, const float* __restrict__ attS,
                       const float* __restrict__ attD, float* __restrict__ aS,
                       float* __restrict__ aD, int N) {
    int i = blockIdx.x * blockDim.x + threadIdx.x;
    if (i >= N * 8) return;
    int n = i >> 3, h = i & 7;
    const float* row = h2 + (size_t)n*64 + h*8;
    float as = 0.f, ad = 0.f;
    #pragma unroll
    for (int c = 0; c < 8; ++c) { float v = row[c]; as += v*attS[h*8+c]; ad += v*attD[h*8+c]; }
    aS[i] = as; aD[i] = ad;
}

// ---- layer 2: per-(node,head) gather softmax + aggregation, no atomics ----
__global__ void k_layer2(const int* __restrict__ offsets, const int* __restrict__ sortedSrc,
                         const float* __restrict__ aS, const float* __restrict__ aD,
                         const float* __restrict__ h2, float* __restrict__ out2, int N) {
    int i = blockIdx.x * blockDim.x + threadIdx.x;
    if (i >= N * 8) return;
    int d = i >> 3, h = i & 7;
    int beg = offsets[d], end = offsets[d+1];
    float ad = aD[(size_t)d*8 + h];
    float m = -3.4e38f;
    for (int e = beg; e < end; ++e) {
        int s = sortedSrc[e];
        m = fmaxf(m, lrelu(aS[(size_t)s*8 + h] + ad));
    }
    float sum = 0.f;
    float a0=0,a1=0,a2=0,a3=0,a4=0,a5=0,a6=0,a7=0;
    for (int e = beg; e < end; ++e) {
        int s = sortedSrc[e];
        float p = expf(lrelu(aS[(size_t)s*8 + h] + ad) - m);
        sum += p;
        const float4* hr = (const float4*)(h2 + (size_t)s*64 + h*8);
        float4 u = hr[0], v = hr[1];
        a0 += p*u.x; a1 += p*u.y; a2 += p*u.z; a3 += p*u.w;
        a4 += p*v.x; a5 += p*v.y; a6 += p*v.z; a7 += p*v.w;
    }
    float inv = 1.f / (sum + SEPS);
    float* orow = out2 + (size_t)d*64 + h*8;
    orow[0]=a0*inv; orow[1]=a1*inv; orow[2]=a2*inv; orow[3]=a3*inv;
    orow[4]=a4*inv; orow[5]=a5*inv; orow[6]=a6*inv; orow[7]=a7*inv;
}

// ---- final: out[n] = sum_j elu(out2[n,j]+b2[j]) * fcw[j] + fcb ----
__global__ void k_final(const float* __restrict__ out2, const float* __restrict__ b2,
                        const float* __restrict__ fcw, const float* __restrict__ fcb,
                        float* __restrict__ out, int N) {
    int n = blockIdx.x * blockDim.x + threadIdx.x;
    if (n >= N) return;
    const float* row = out2 + (size_t)n * 64;
    float acc = fcb[0];
    #pragma unroll
    for (int j = 0; j < 64; ++j) acc += elu1(row[j] + b2[j]) * fcw[j];
    out[n] = acc;
}

extern "C" void kernel_launch(void* const* d_in, const int* in_sizes, int n_in,
                              void* d_out, int out_size, void* d_ws, size_t ws_size,
                              hipStream_t stream) {
    const float* x    = (const float*)d_in[0];
    const int*   ei   = (const int*)  d_in[1];
    const float* W1   = (const float*)d_in[2];
    const float* as1  = (const float*)d_in[3];
    const float* ad1  = (const float*)d_in[4];
    const float* b1   = (const float*)d_in[5];
    const float* W2   = (const float*)d_in[6];
    const float* attS2= (const float*)d_in[7];
    const float* attD2= (const float*)d_in[8];
    const float* b2   = (const float*)d_in[9];
    const float* fcw  = (const float*)d_in[10];
    const float* fcb  = (const float*)d_in[11];
    float* out = (float*)d_out;

    int N = in_sizes[0];          // x is [N,1]
    int E = in_sizes[1] / 2;      // edge_index is [2,E]
    int ET = E + N;               // with self-loops

    const int* srcI = ei;
    const int* dstI = ei + E;

    float* ws = (float*)d_ws;
    size_t off = 0;
    float* SD        = ws + off; off += 8;
    int*   counts    = (int*)(ws + off); off += (size_t)N;
    int*   partial   = (int*)(ws + off); off += (size_t)N;
    int*   blockSums = (int*)(ws + off); off += 512;
    int*   offsets   = (int*)(ws + off); off += (size_t)N + 8;   // N+1, padded
    int*   cursor    = (int*)(ws + off); off += (size_t)N;
    int*   sortedSrc = (int*)(ws + off); off += (size_t)ET;
    float* aS2       = ws + off; off += (size_t)N * 8;
    float* aD2       = ws + off; off += (size_t)N * 8;
    float* h2        = ws + off; off += (size_t)N * 64;
    float* out1p     = ws + off; off += (size_t)N * 32;
    float* out2      = ws + off; off += (size_t)N * 64;

    hipMemsetAsync(counts, 0, (size_t)N * sizeof(int), stream);

    k_prep1<<<1, 64, 0, stream>>>(W1, as1, ad1, SD);

    int gE  = (ET + TPB - 1) / TPB;
    int gN  = (N + TPB - 1) / TPB;
    int nb  = (N + SCAN_B - 1) / SCAN_B;

    k_hist   <<<gE, TPB, 0, stream>>>(dstI, E, N, counts);
    k_scan1  <<<nb, SCAN_B, 0, stream>>>(counts, partial, blockSums, N);
    k_scan2  <<<1, 512, 0, stream>>>(blockSums, nb);
    k_scan3  <<<gN, TPB, 0, stream>>>(partial, blockSums, offsets, cursor, N, ET);
    k_scatter<<<gE, TPB, 0, stream>>>(srcI, dstI, E, N, cursor, sortedSrc);

    k_layer1 <<<gN, TPB, 0, stream>>>(offsets, sortedSrc, x, SD, W1, b1, out1p, N);
    k_h2     <<<(N*64 + TPB - 1) / TPB, TPB, 0, stream>>>(out1p, W2, h2, N);
    k_att2   <<<(N*8 + TPB - 1) / TPB, TPB, 0, stream>>>(h2, attS2, attD2, aS2, aD2, N);
    k_layer2 <<<(N*8 + TPB - 1) / TPB, TPB, 0, stream>>>(offsets, sortedSrc, aS2, aD2, h2, out2, N);
    k_final  <<<gN, TPB, 0, stream>>>(out2, b2, fcw, fcb, out, N);
}

// Round 3
// 477.276 us; speedup vs baseline: 17.5522x; 1.1238x over previous
//
#include <hip/hip_runtime.h>
#include <cmath>

#define TPB 256
#define NSLOPE 0.2f
#define SEPS 1e-16f

__device__ __forceinline__ float lrelu(float v) { return v > 0.f ? v : NSLOPE * v; }
__device__ __forceinline__ float elu1(float v)  { return v > 0.f ? v : expm1f(v); }

// ---- layer-1 scalar prep: SD[0..3]=S1[h]=sum_c W1[h,c]*att_src1[h,c]; SD[4..7]=D1 ----
__global__ void k_prep1(const float* __restrict__ W1, const float* __restrict__ as1,
                        const float* __restrict__ ad1, float* __restrict__ SD) {
    int t = threadIdx.x;
    if (t < 8) {
        int h = t & 3;
        const float* att = (t >= 4) ? ad1 : as1;
        float acc = 0.f;
        #pragma unroll
        for (int c = 0; c < 8; ++c) acc += W1[h*8+c] * att[h*8+c];
        SD[t] = acc;
    }
}

// ---- counting sort by dst; counters padded to 1/cache-line (stride 16 ints) ----
__global__ void k_hist(const int* __restrict__ dstI, int E, int N, int* __restrict__ counts_p) {
    int e = blockIdx.x * blockDim.x + threadIdx.x;
    if (e >= E + N) return;
    int d = (e < E) ? dstI[e] : (e - E);
    atomicAdd(&counts_p[(size_t)d * 16], 1);
}

#define SCAN_B 256
__global__ void k_scan1(const int* __restrict__ counts_p, int* __restrict__ partial,
                        int* __restrict__ blockSums, int N) {
    __shared__ int tmp[SCAN_B];
    int gid = blockIdx.x * SCAN_B + threadIdx.x;
    int v = (gid < N) ? counts_p[(size_t)gid * 16] : 0;
    tmp[threadIdx.x] = v;
    __syncthreads();
    for (int off = 1; off < SCAN_B; off <<= 1) {
        int t = (threadIdx.x >= off) ? tmp[threadIdx.x - off] : 0;
        __syncthreads();
        tmp[threadIdx.x] += t;
        __syncthreads();
    }
    if (gid < N) partial[gid] = tmp[threadIdx.x] - v;          // exclusive within block
    if (threadIdx.x == SCAN_B - 1) blockSums[blockIdx.x] = tmp[SCAN_B - 1];
}

__global__ void k_scan2(int* __restrict__ blockSums, int nb) {
    __shared__ int tmp[512];
    int t = threadIdx.x;
    int v = (t < nb) ? blockSums[t] : 0;
    tmp[t] = v;
    __syncthreads();
    for (int off = 1; off < 512; off <<= 1) {
        int u = (t >= off) ? tmp[t - off] : 0;
        __syncthreads();
        tmp[t] += u;
        __syncthreads();
    }
    if (t < nb) blockSums[t] = tmp[t] - v;                     // exclusive
}

__global__ void k_scan3(const int* __restrict__ partial, const int* __restrict__ blockSums,
                        int* __restrict__ offsets, int* __restrict__ cursor_p, int N, int ET) {
    int gid = blockIdx.x * blockDim.x + threadIdx.x;
    if (gid >= N) return;
    int v = partial[gid] + blockSums[gid / SCAN_B];
    offsets[gid] = v;
    cursor_p[(size_t)gid * 16] = v;
    if (gid == 0) offsets[N] = ET;
}

__global__ void k_scatter(const int* __restrict__ srcI, const int* __restrict__ dstI,
                          int E, int N, int* __restrict__ cursor_p, int* __restrict__ sortedSrc) {
    int e = blockIdx.x * blockDim.x + threadIdx.x;
    if (e >= E + N) return;
    int s, d;
    if (e < E) { s = srcI[e]; d = dstI[e]; } else { s = d = e - E; }
    int pos = atomicAdd(&cursor_p[(size_t)d * 16], 1);
    __builtin_nontemporal_store(s, &sortedSrc[pos]);
}

// ---- layer 1 fused: single-pass gather softmax (H=4, no max-shift) -> bias -> ELU ----
// h1[s,h,c] = x[s]*W1[h,c]  =>  sum_e alpha*h1[s] = (sum_e alpha*x[s]) * W1[h,:]
__global__ void k_layer1(const int* __restrict__ offsets, const int* __restrict__ sortedSrc,
                         const float* __restrict__ x, const float* __restrict__ SD,
                         const float* __restrict__ W1, const float* __restrict__ b1,
                         float* __restrict__ out1p, int N) {
    int d = blockIdx.x * blockDim.x + threadIdx.x;
    if (d >= N) return;
    int beg = offsets[d], end = offsets[d+1];
    float xd = x[d];
    float S0 = SD[0], S1 = SD[1], S2 = SD[2], S3 = SD[3];
    float D0 = xd*SD[4], D1 = xd*SD[5], D2 = xd*SD[6], D3 = xd*SD[7];
    float s0 = 0.f, s1 = 0.f, s2 = 0.f, s3 = 0.f;
    float g0 = 0.f, g1 = 0.f, g2 = 0.f, g3 = 0.f;
    for (int i = beg; i < end; ++i) {
        float xs = x[sortedSrc[i]];
        float p;
        p = expf(lrelu(xs*S0 + D0)); s0 += p; g0 += p * xs;
        p = expf(lrelu(xs*S1 + D1)); s1 += p; g1 += p * xs;
        p = expf(lrelu(xs*S2 + D2)); s2 += p; g2 += p * xs;
        p = expf(lrelu(xs*S3 + D3)); s3 += p; g3 += p * xs;
    }
    float g[4];
    g[0] = g0 / (s0 + SEPS); g[1] = g1 / (s1 + SEPS);
    g[2] = g2 / (s2 + SEPS); g[3] = g3 / (s3 + SEPS);
    float* orow = out1p + (size_t)d * 32;
    #pragma unroll
    for (int h = 0; h < 4; ++h)
        #pragma unroll
        for (int c = 0; c < 8; ++c)
            orow[h*8+c] = elu1(g[h] * W1[h*8+c] + b1[h*8+c]);
}

// ---- h2[n,j] = sum_k out1p[n,k]*W2[k,j] fused with att coeffs (waves are node-aligned) ----
__global__ void k_h2att(const float* __restrict__ h1p, const float* __restrict__ W2,
                        const float* __restrict__ attS, const float* __restrict__ attD,
                        float* __restrict__ h2, float* __restrict__ aS, float* __restrict__ aD,
                        int N) {
    int i = blockIdx.x * blockDim.x + threadIdx.x;
    if (i >= N * 64) return;
    int n = i >> 6, j = i & 63;
    const float* row = h1p + (size_t)n * 32;
    float acc = 0.f;
    #pragma unroll
    for (int k = 0; k < 32; ++k) acc += row[k] * W2[k*64 + j];
    h2[i] = acc;
    // per-head reductions over c = j&7 (lanes j = h*8+c, all within one wave)
    float ps = acc * attS[j];
    float pd = acc * attD[j];
    #pragma unroll
    for (int m = 1; m < 8; m <<= 1) {
        ps += __shfl_xor(ps, m);
        pd += __shfl_xor(pd, m);
    }
    int h = j >> 3, c = j & 7;
    if (c == 0) aS[(size_t)n*8 + h] = ps;
    if (c == 1) aD[(size_t)n*8 + h] = pd;
}

// ---- layer 2: wave-per-node gather softmax + aggregation + fused bias/ELU/fc epilogue ----
__global__ void k_layer2f(const int* __restrict__ offsets, const int* __restrict__ ss,
                          const float* __restrict__ aS, const float* __restrict__ aD,
                          const float* __restrict__ h2, const float* __restrict__ b2,
                          const float* __restrict__ fcw, const float* __restrict__ fcb,
                          float* __restrict__ out, int N) {
    int lane = threadIdx.x & 63;
    int d = blockIdx.x * 4 + (threadIdx.x >> 6);
    if (d >= N) return;
    int h = lane >> 3;
    int beg = offsets[d], end = offsets[d+1];
    float ad = aD[(size_t)d*8 + h];
    float sum = 0.f, acc = 0.f;
    int e = beg;
    for (; e + 4 <= end; e += 4) {
        int s0 = ss[e], s1 = ss[e+1], s2 = ss[e+2], s3 = ss[e+3];
        float v0 = aS[(size_t)s0*8 + h], v1 = aS[(size_t)s1*8 + h];
        float v2 = aS[(size_t)s2*8 + h], v3 = aS[(size_t)s3*8 + h];
        float g0 = h2[(size_t)s0*64 + lane], g1 = h2[(size_t)s1*64 + lane];
        float g2 = h2[(size_t)s2*64 + lane], g3 = h2[(size_t)s3*64 + lane];
        float p0 = expf(lrelu(v0 + ad)), p1 = expf(lrelu(v1 + ad));
        float p2 = expf(lrelu(v2 + ad)), p3 = expf(lrelu(v3 + ad));
        sum += (p0 + p1) + (p2 + p3);
        acc += p0*g0 + p1*g1 + p2*g2 + p3*g3;
    }
    for (; e < end; ++e) {
        int s = ss[e];
        float p = expf(lrelu(aS[(size_t)s*8 + h] + ad));
        sum += p;
        acc += p * h2[(size_t)s*64 + lane];
    }
    float r = acc / (sum + SEPS);
    float t = elu1(r + b2[lane]) * fcw[lane];
    #pragma unroll
    for (int m = 32; m; m >>= 1) t += __shfl_xor(t, m);
    if (lane == 0) out[d] = t + fcb[0];
}

extern "C" void kernel_launch(void* const* d_in, const int* in_sizes, int n_in,
                              void* d_out, int out_size, void* d_ws, size_t ws_size,
                              hipStream_t stream) {
    const float* x    = (const float*)d_in[0];
    const int*   ei   = (const int*)  d_in[1];
    const float* W1   = (const float*)d_in[2];
    const float* as1  = (const float*)d_in[3];
    const float* ad1  = (const float*)d_in[4];
    const float* b1   = (const float*)d_in[5];
    const float* W2   = (const float*)d_in[6];
    const float* attS2= (const float*)d_in[7];
    const float* attD2= (const float*)d_in[8];
    const float* b2   = (const float*)d_in[9];
    const float* fcw  = (const float*)d_in[10];
    const float* fcb  = (const float*)d_in[11];
    float* out = (float*)d_out;

    int N = in_sizes[0];          // x is [N,1]
    int E = in_sizes[1] / 2;      // edge_index is [2,E]
    int ET = E + N;               // with self-loops

    const int* srcI = ei;
    const int* dstI = ei + E;

    float* ws = (float*)d_ws;
    size_t off = 0;
    float* SD        = ws + off; off += 16;                        // padded to 64B
    int*   counts_p  = (int*)(ws + off); off += (size_t)N * 16;    // 1 counter / 64B line
    int*   cursor_p  = (int*)(ws + off); off += (size_t)N * 16;
    int*   partial   = (int*)(ws + off); off += (size_t)N;
    int*   blockSums = (int*)(ws + off); off += 512;
    int*   offsets   = (int*)(ws + off); off += (size_t)N + 16;
    int*   sortedSrc = (int*)(ws + off); off += (size_t)ET;
    float* aS2       = ws + off; off += (size_t)N * 8;
    float* aD2       = ws + off; off += (size_t)N * 8;
    float* h2        = ws + off; off += (size_t)N * 64;
    float* out1p     = ws + off; off += (size_t)N * 32;

    hipMemsetAsync(counts_p, 0, (size_t)N * 16 * sizeof(int), stream);

    k_prep1<<<1, 64, 0, stream>>>(W1, as1, ad1, SD);

    int gE  = (ET + TPB - 1) / TPB;
    int gN  = (N + TPB - 1) / TPB;
    int nb  = (N + SCAN_B - 1) / SCAN_B;

    k_hist   <<<gE, TPB, 0, stream>>>(dstI, E, N, counts_p);
    k_scan1  <<<nb, SCAN_B, 0, stream>>>(counts_p, partial, blockSums, N);
    k_scan2  <<<1, 512, 0, stream>>>(blockSums, nb);
    k_scan3  <<<gN, TPB, 0, stream>>>(partial, blockSums, offsets, cursor_p, N, ET);
    k_scatter<<<gE, TPB, 0, stream>>>(srcI, dstI, E, N, cursor_p, sortedSrc);

    k_layer1 <<<gN, TPB, 0, stream>>>(offsets, sortedSrc, x, SD, W1, b1, out1p, N);
    k_h2att  <<<(N*64 + TPB - 1) / TPB, TPB, 0, stream>>>(out1p, W2, attS2, attD2, h2, aS2, aD2, N);
    k_layer2f<<<(N + 3) / 4, TPB, 0, stream>>>(offsets, sortedSrc, aS2, aD2, h2, b2, fcw, fcb, out, N);
}

// Round 4
// 331.534 us; speedup vs baseline: 25.2681x; 1.4396x over previous
//
#include <hip/hip_runtime.h>
#include <cmath>

#define TPB 256
#define NSLOPE 0.2f
#define SEPS 1e-16f

#define BSH 8                 // nodes per bucket = 256
#define BSZ 256
#define NBMAX 1024            // supports N up to 262144
#define NCHUNK 256            // blocks for bucket hist/scatter

__device__ __forceinline__ float lrelu(float v) { return v > 0.f ? v : NSLOPE * v; }
__device__ __forceinline__ float elu1(float v)  { return v > 0.f ? v : expm1f(v); }

// ---- layer-1 scalar prep: SD[0..3]=S1[h]=sum_c W1[h,c]*att_src1[h,c]; SD[4..7]=D1 ----
__global__ void k_prep1(const float* __restrict__ W1, const float* __restrict__ as1,
                        const float* __restrict__ ad1, float* __restrict__ SD) {
    int t = threadIdx.x;
    if (t < 8) {
        int h = t & 3;
        const float* att = (t >= 4) ? ad1 : as1;
        float acc = 0.f;
        #pragma unroll
        for (int c = 0; c < 8; ++c) acc += W1[h*8+c] * att[h*8+c];
        SD[t] = acc;
    }
}

// ---- pass A: coarse bucket histogram (LDS, then ~NB global atomics per block) ----
__global__ void k_bhist(const int* __restrict__ dstI, int E, int N, int NB, int chunk,
                        int* __restrict__ bucketCnt) {
    __shared__ int cnt[NBMAX];
    for (int i = threadIdx.x; i < NB; i += blockDim.x) cnt[i] = 0;
    __syncthreads();
    int ET = E + N;
    int beg = blockIdx.x * chunk;
    int end = min(beg + chunk, ET);
    for (int e = beg + threadIdx.x; e < end; e += blockDim.x) {
        int d = (e < E) ? dstI[e] : (e - E);
        atomicAdd(&cnt[d >> BSH], 1);
    }
    __syncthreads();
    for (int i = threadIdx.x; i < NB; i += blockDim.x)
        if (cnt[i]) atomicAdd(&bucketCnt[i], cnt[i]);
}

// ---- pass B: one-block exclusive scan of bucket counts ----
__global__ void k_bscan(const int* __restrict__ bucketCnt, int* __restrict__ bucketBase,
                        int* __restrict__ bucketCursor, int NB, int ET,
                        int* __restrict__ offsets, int N) {
    __shared__ int tmp[NBMAX];
    int t = threadIdx.x;
    int v = (t < NB) ? bucketCnt[t] : 0;
    tmp[t] = v;
    __syncthreads();
    for (int off = 1; off < NBMAX; off <<= 1) {
        int u = (t >= off) ? tmp[t - off] : 0;
        __syncthreads();
        tmp[t] += u;
        __syncthreads();
    }
    if (t < NB) { int ex = tmp[t] - v; bucketBase[t] = ex; bucketCursor[t] = ex; }
    if (t == 0) { bucketBase[NB] = ET; offsets[N] = ET; }
}

// ---- pass C: bucket scatter of (src,dst) pairs; one claim-atomic per (block,bucket) ----
__global__ void k_bscatter(const int* __restrict__ srcI, const int* __restrict__ dstI,
                           int E, int N, int NB, int chunk,
                           int* __restrict__ bucketCursor, int2* __restrict__ pk) {
    __shared__ int cnt[NBMAX];
    __shared__ int base[NBMAX];
    for (int i = threadIdx.x; i < NB; i += blockDim.x) cnt[i] = 0;
    __syncthreads();
    int ET = E + N;
    int beg = blockIdx.x * chunk;
    int end = min(beg + chunk, ET);
    for (int e = beg + threadIdx.x; e < end; e += blockDim.x) {
        int d = (e < E) ? dstI[e] : (e - E);
        atomicAdd(&cnt[d >> BSH], 1);
    }
    __syncthreads();
    for (int i = threadIdx.x; i < NB; i += blockDim.x) {
        base[i] = cnt[i] ? atomicAdd(&bucketCursor[i], cnt[i]) : 0;
        cnt[i] = 0;
    }
    __syncthreads();
    for (int e = beg + threadIdx.x; e < end; e += blockDim.x) {
        int s, d;
        if (e < E) { s = srcI[e]; d = dstI[e]; } else { s = d = e - E; }
        int b = d >> BSH;
        int r = atomicAdd(&cnt[b], 1);
        pk[base[b] + r] = make_int2(s, d);
    }
}

// ---- pass D: per-bucket fine sort (LDS count+scan), emits offsets[] and sortedSrc ----
__global__ void k_bsort(const int2* __restrict__ pk, const int* __restrict__ bucketBase,
                        int N, int* __restrict__ offsets, int* __restrict__ sortedSrc) {
    __shared__ int cnt[BSZ];
    __shared__ int offl[BSZ];
    int b = blockIdx.x;
    int rbeg = bucketBase[b], rend = bucketBase[b + 1];
    int t = threadIdx.x;                    // 256 threads
    cnt[t] = 0;
    __syncthreads();
    for (int i = rbeg + t; i < rend; i += BSZ) {
        int2 p = pk[i];
        atomicAdd(&cnt[p.y & (BSZ - 1)], 1);
    }
    __syncthreads();
    int v = cnt[t];
    offl[t] = v;
    __syncthreads();
    for (int off = 1; off < BSZ; off <<= 1) {
        int u = (t >= off) ? offl[t - off] : 0;
        __syncthreads();
        offl[t] += u;
        __syncthreads();
    }
    int ex = offl[t] - v;                   // exclusive prefix within bucket
    int d = (b << BSH) + t;
    if (d < N) offsets[d] = rbeg + ex;
    cnt[t] = 0;                             // reuse as per-node cursor
    offl[t] = ex;
    __syncthreads();
    for (int i = rbeg + t; i < rend; i += BSZ) {
        int2 p = pk[i];
        int dl = p.y & (BSZ - 1);
        int r = atomicAdd(&cnt[dl], 1);
        sortedSrc[rbeg + offl[dl] + r] = p.x;
    }
}

// ---- layer 1 fused: single-pass gather softmax (H=4) -> bias -> ELU ----
// h1[s,h,c] = x[s]*W1[h,c]  =>  sum_e alpha*h1[s] = (sum_e alpha*x[s]) * W1[h,:]
__global__ void k_layer1(const int* __restrict__ offsets, const int* __restrict__ sortedSrc,
                         const float* __restrict__ x, const float* __restrict__ SD,
                         const float* __restrict__ W1, const float* __restrict__ b1,
                         float* __restrict__ out1p, int N) {
    int d = blockIdx.x * blockDim.x + threadIdx.x;
    if (d >= N) return;
    int beg = offsets[d], end = offsets[d+1];
    float xd = x[d];
    float S0 = SD[0], S1 = SD[1], S2 = SD[2], S3 = SD[3];
    float D0 = xd*SD[4], D1 = xd*SD[5], D2 = xd*SD[6], D3 = xd*SD[7];
    float s0 = 0.f, s1 = 0.f, s2 = 0.f, s3 = 0.f;
    float g0 = 0.f, g1 = 0.f, g2 = 0.f, g3 = 0.f;
    for (int i = beg; i < end; ++i) {
        float xs = x[sortedSrc[i]];
        float p;
        p = expf(lrelu(xs*S0 + D0)); s0 += p; g0 += p * xs;
        p = expf(lrelu(xs*S1 + D1)); s1 += p; g1 += p * xs;
        p = expf(lrelu(xs*S2 + D2)); s2 += p; g2 += p * xs;
        p = expf(lrelu(xs*S3 + D3)); s3 += p; g3 += p * xs;
    }
    float g[4];
    g[0] = g0 / (s0 + SEPS); g[1] = g1 / (s1 + SEPS);
    g[2] = g2 / (s2 + SEPS); g[3] = g3 / (s3 + SEPS);
    float* orow = out1p + (size_t)d * 32;
    #pragma unroll
    for (int h = 0; h < 4; ++h)
        #pragma unroll
        for (int c = 0; c < 8; ++c)
            orow[h*8+c] = elu1(g[h] * W1[h*8+c] + b1[h*8+c]);
}

// ---- h2[n,j] = sum_k out1p[n,k]*W2[k,j] fused with att coeffs (waves node-aligned) ----
__global__ void k_h2att(const float* __restrict__ h1p, const float* __restrict__ W2,
                        const float* __restrict__ attS, const float* __restrict__ attD,
                        float* __restrict__ h2, float* __restrict__ aS, float* __restrict__ aD,
                        int N) {
    int i = blockIdx.x * blockDim.x + threadIdx.x;
    if (i >= N * 64) return;
    int n = i >> 6, j = i & 63;
    const float* row = h1p + (size_t)n * 32;
    float acc = 0.f;
    #pragma unroll
    for (int k = 0; k < 32; ++k) acc += row[k] * W2[k*64 + j];
    h2[i] = acc;
    float ps = acc * attS[j];
    float pd = acc * attD[j];
    #pragma unroll
    for (int m = 1; m < 8; m <<= 1) {
        ps += __shfl_xor(ps, m);
        pd += __shfl_xor(pd, m);
    }
    int h = j >> 3, c = j & 7;
    if (c == 0) aS[(size_t)n*8 + h] = ps;
    if (c == 1) aD[(size_t)n*8 + h] = pd;
}

// ---- layer 2: wave-per-node gather softmax + aggregation + fused bias/ELU/fc ----
__global__ void k_layer2f(const int* __restrict__ offsets, const int* __restrict__ ss,
                          const float* __restrict__ aS, const float* __restrict__ aD,
                          const float* __restrict__ h2, const float* __restrict__ b2,
                          const float* __restrict__ fcw, const float* __restrict__ fcb,
                          float* __restrict__ out, int N) {
    int lane = threadIdx.x & 63;
    int d = blockIdx.x * 4 + (threadIdx.x >> 6);
    if (d >= N) return;
    int h = lane >> 3;
    int beg = offsets[d], end = offsets[d+1];
    float ad = aD[(size_t)d*8 + h];
    float sum = 0.f, acc = 0.f;
    int e = beg;
    for (; e + 4 <= end; e += 4) {
        int s0 = ss[e], s1 = ss[e+1], s2 = ss[e+2], s3 = ss[e+3];
        float v0 = aS[(size_t)s0*8 + h], v1 = aS[(size_t)s1*8 + h];
        float v2 = aS[(size_t)s2*8 + h], v3 = aS[(size_t)s3*8 + h];
        float g0 = h2[(size_t)s0*64 + lane], g1 = h2[(size_t)s1*64 + lane];
        float g2 = h2[(size_t)s2*64 + lane], g3 = h2[(size_t)s3*64 + lane];
        float p0 = expf(lrelu(v0 + ad)), p1 = expf(lrelu(v1 + ad));
        float p2 = expf(lrelu(v2 + ad)), p3 = expf(lrelu(v3 + ad));
        sum += (p0 + p1) + (p2 + p3);
        acc += p0*g0 + p1*g1 + p2*g2 + p3*g3;
    }
    for (; e < end; ++e) {
        int s = ss[e];
        float p = expf(lrelu(aS[(size_t)s*8 + h] + ad));
        sum += p;
        acc += p * h2[(size_t)s*64 + lane];
    }
    float r = acc / (sum + SEPS);
    float t = elu1(r + b2[lane]) * fcw[lane];
    #pragma unroll
    for (int m = 32; m; m >>= 1) t += __shfl_xor(t, m);
    if (lane == 0) out[d] = t + fcb[0];
}

extern "C" void kernel_launch(void* const* d_in, const int* in_sizes, int n_in,
                              void* d_out, int out_size, void* d_ws, size_t ws_size,
                              hipStream_t stream) {
    const float* x    = (const float*)d_in[0];
    const int*   ei   = (const int*)  d_in[1];
    const float* W1   = (const float*)d_in[2];
    const float* as1  = (const float*)d_in[3];
    const float* ad1  = (const float*)d_in[4];
    const float* b1   = (const float*)d_in[5];
    const float* W2   = (const float*)d_in[6];
    const float* attS2= (const float*)d_in[7];
    const float* attD2= (const float*)d_in[8];
    const float* b2   = (const float*)d_in[9];
    const float* fcw  = (const float*)d_in[10];
    const float* fcb  = (const float*)d_in[11];
    float* out = (float*)d_out;

    int N = in_sizes[0];          // x is [N,1]
    int E = in_sizes[1] / 2;      // edge_index is [2,E]
    int ET = E + N;               // with self-loops
    int NB = (N + BSZ - 1) / BSZ; // coarse buckets (<= NBMAX)

    const int* srcI = ei;
    const int* dstI = ei + E;

    float* ws = (float*)d_ws;
    size_t off = 0;
    float* SD           = ws + off; off += 16;
    int*   bucketCnt    = (int*)(ws + off); off += NBMAX;
    int*   bucketBase   = (int*)(ws + off); off += NBMAX + 16;
    int*   bucketCursor = (int*)(ws + off); off += NBMAX;
    int*   offsets      = (int*)(ws + off); off += (size_t)N + 16;
    off = (off + 1) & ~(size_t)1;                       // 8B align for int2
    int2*  pk           = (int2*)(ws + off); off += (size_t)ET * 2;
    int*   sortedSrc    = (int*)(ws + off); off += (size_t)ET;
    float* aS2          = ws + off; off += (size_t)N * 8;
    float* aD2          = ws + off; off += (size_t)N * 8;
    float* h2           = ws + off; off += (size_t)N * 64;
    float* out1p        = ws + off; off += (size_t)N * 32;

    hipMemsetAsync(bucketCnt, 0, NBMAX * sizeof(int), stream);

    k_prep1<<<1, 64, 0, stream>>>(W1, as1, ad1, SD);

    int chunk = (ET + NCHUNK - 1) / NCHUNK;
    k_bhist   <<<NCHUNK, TPB, 0, stream>>>(dstI, E, N, NB, chunk, bucketCnt);
    k_bscan   <<<1, NBMAX, 0, stream>>>(bucketCnt, bucketBase, bucketCursor, NB, ET, offsets, N);
    k_bscatter<<<NCHUNK, TPB, 0, stream>>>(srcI, dstI, E, N, NB, chunk, bucketCursor, pk);
    k_bsort   <<<NB, BSZ, 0, stream>>>(pk, bucketBase, N, offsets, sortedSrc);

    int gN = (N + TPB - 1) / TPB;
    k_layer1 <<<gN, TPB, 0, stream>>>(offsets, sortedSrc, x, SD, W1, b1, out1p, N);
    k_h2att  <<<(N*64 + TPB - 1) / TPB, TPB, 0, stream>>>(out1p, W2, attS2, attD2, h2, aS2, aD2, N);
    k_layer2f<<<(N + 3) / 4, TPB, 0, stream>>>(offsets, sortedSrc, aS2, aD2, h2, b2, fcw, fcb, out, N);
}